// Round 7
// baseline (113.842 us; speedup 1.0000x reference)
//
#include <hip/hip_runtime.h>

// VQVAE quantize.  x: [8,64,32,32] fp32, codebook: [8192,64] fp32.
// d_out (fp32, concat): [0,524288) quant_out | [524288] commit_loss |
//                       [524289] codebook_loss | [524290,532482) indices
//
// argmin via fp16x2 emulated-fp32 MFMA GEMM (3 terms):
//   v = h + m (2 fp16, exact to ~|v|*2^-23); dot ~= hh + hm + mh
//   score = dot - 0.5*e2[k]  (argmax score == argmin d2; absmax 0 R12-R24)
//
// R24 post-mortem: prep-8x + final-merge neutral (within +-4us noise)
// -> accounting: dur ~= fill(41, harness, untouchable) + argmin(~37)
// + gather(~7) + prep(~2) + gaps. argmin is the only lever left; it
// runs ~3x over its 13us MFMA floor.
// R25 theory: no-LDS M=2 design loads B per WAVE (64KB x 8192 waves =
// 512MB L1 traffic; 5 loads per 12 MFMA) and R19 counters showed
// VALU+load-issue >= MFMA. B-traffic scales 1/M; M=4 halves it and
// halves per-wave fixed costs (af build, addressing) at constant MFMA
// and select totals. grid (32,32)=1024 blk x 256 thr, lb(256,3)
// (~170-reg budget; est 150-165). Per-s bf loads trim transients.
// R22 lesson: combined VGPR+AGPR budget caps waves/SIMD (unified file).
// R21 lesson: chunk loop stays rolled. R13: 4-tile tl clusters only.

#define N_PTS   8192
#define K_CODES 8192
#define C_DIM   64
#define HWSZ    1024
#define QOUT_N  524288
#define SPLITS  32            // codes per split = 256 = 4 chunks of 64
#define NCH     4             // chunks per split

// ---- workspace layout (bytes) ----
#define WS_PACK  0            // u64 [32][8192]       = 2097152
#define WS_CBS   2097152      // u16 [2*8][8192][8]   = 2097152
#define WS_E2H   4194304      // float [8192]         = 32768
#define WS_PART  4227072      // float [1024]         = 4096
#define WS_TICK  4231168      // int                  = 4

typedef __attribute__((ext_vector_type(8))) short    short8;
typedef __attribute__((ext_vector_type(8))) _Float16 half8;
typedef __attribute__((ext_vector_type(4))) float    floatx4;

__device__ __forceinline__ half8 as_h8(short8 v) {
    return __builtin_bit_cast(half8, v);
}
__device__ __forceinline__ void split2(float v, unsigned short& h,
                                       unsigned short& m) {
    _Float16 hh = (_Float16)v;                     // RNE
    float r = v - (float)hh;
    _Float16 mm = (_Float16)r;
    h = __builtin_bit_cast(unsigned short, hh);
    m = __builtin_bit_cast(unsigned short, mm);
}

// ============================================================
// Kernel A: prep — codebook split + e2. 256 blocks x 256 thr,
// one thread per (code row k, channel octet g): loads 32B
// contiguous (coalesced), split2 x8, two 16B plane writes;
// e2[k] via shfl_xor over the 8 g-lanes of the row. Zeroes the
// gather ticket.
// Plane layout [p*8+g][k][8], p in {0=h,1=m}: 16B per
// (code, c-octet g) == one MFMA fragment k-group.
// ============================================================
__global__ __launch_bounds__(256)
void vq_prep_kernel(const float* __restrict__ cb,
                    unsigned short* __restrict__ cbS,
                    float* __restrict__ e2h,
                    int* __restrict__ ticket)
{
    const int gt = blockIdx.x * 256 + threadIdx.x;   // 0..65535
    const int k  = gt >> 3;
    const int g  = gt & 7;
    if (gt == 0) *ticket = 0;

    const float* rp = cb + (size_t)k * C_DIM + g * 8;
    float4 a = *(const float4*)(rp);
    float4 b = *(const float4*)(rp + 4);
    float vv[8] = {a.x, a.y, a.z, a.w, b.x, b.y, b.z, b.w};
    unsigned short h8[8], m8[8];
    float s = 0.0f;
    #pragma unroll
    for (int j = 0; j < 8; ++j) {
        s = fmaf(vv[j], vv[j], s);
        split2(vv[j], h8[j], m8[j]);
    }
    *(uint4*)(cbS + ((size_t)(0 * 8 + g) * 8192 + k) * 8) = *(const uint4*)h8;
    *(uint4*)(cbS + ((size_t)(1 * 8 + g) * 8192 + k) * 8) = *(const uint4*)m8;

    #pragma unroll
    for (int msk = 1; msk < 8; msk <<= 1) s += __shfl_xor(s, msk, 64);
    if (g == 0) e2h[k] = 0.5f * s;
}

// ============================================================
// Kernel B: argmin via 16x16x32 f16 MFMA. grid (32 m-blocks,
// 32 splits) = 1024 blocks x 256 threads (4 waves). Wave owns
// 64 points (4 tiles of 16) x 256 codes — M=4 halves per-code
// B-traffic vs M=2 (B loads amortize over 4 point-tiles).
// NO LDS, NO barriers: per 16-code tile, bf (per-s, 2x dwordx4)
// and e2 read straight from global (16KB chunk L1-resident;
// co-resident blocks share the split). A-frags from x (64 regs).
// lb(256,3): 3 waves/SIMD = 3 blocks/CU co-resident.
// Final reduce via __shfl_xor u64 min (16 owner cols, R19 map).
// Layouts (verified m89/m91/m120): A[m=lane&15][k=quad*8+j],
// B[k=quad*8+j][n=lane&15], C: col=lane&15, row=quad*4+reg.
// ============================================================
__global__ __launch_bounds__(256, 3)
void vq_argmin_kernel(const float* __restrict__ x,
                      const unsigned short* __restrict__ cbS,
                      const float* __restrict__ e2h,
                      unsigned long long* __restrict__ packedS)
{
    const int tid   = threadIdx.x;       // 0..255
    const int lane  = tid & 63;
    const int w     = tid >> 6;          // 0..3
    const int col   = lane & 15;
    const int quad  = lane >> 4;
    const int mb    = blockIdx.x;        // 0..31
    const int split = blockIdx.y;        // 0..31
    const int m0    = mb * 256 + w * 64;
    const int nb0   = split * 256;

    // A fragments straight from x: pt = m0 + t*16 + col, channel
    // c = s*32 + quad*8 + j (matches MFMA k = quad*8+j per s-step).
    // 256 pts per block never cross an image (1024 pts/image).
    const int bimg = m0 >> 10;
    const int hw0  = m0 & 1023;
    const float* xb = x + (size_t)bimg * (C_DIM * HWSZ);
    half8 af[4][2][2];                   // [tile][plane][s] = 64 regs
    #pragma unroll
    for (int t = 0; t < 4; ++t) {
        const int hw = hw0 + t * 16 + col;
        #pragma unroll
        for (int s = 0; s < 2; ++s) {
            unsigned short h8[8], m8[8];
            #pragma unroll
            for (int j = 0; j < 8; ++j) {
                float v = xb[(size_t)(s * 32 + quad * 8 + j) * HWSZ + hw];
                split2(v, h8[j], m8[j]);
            }
            af[t][0][s] = as_h8(*(const short8*)h8);
            af[t][1][s] = as_h8(*(const short8*)m8);
        }
    }

    float bestv[4][4];
    int   besti[4][4];
    #pragma unroll
    for (int t = 0; t < 4; ++t)
        #pragma unroll
        for (int r = 0; r < 4; ++r) {
            bestv[t][r] = __uint_as_float(0xFF800000u);  // -inf
            besti[t][r] = 0;
        }

    // main loop: 4 chunks x 4 tiles of 16 codes; everything from
    // global (L1). Rolled ch loop (R21: unroll -> spill); tl loop
    // unrolled so the compiler pipelines loads across tiles.
    // Per tile: 2x(2 b128 loads + 12 MFMA) + 16 selects.
    #pragma clang loop unroll(disable)
    for (int ch = 0; ch < NCH; ++ch) {
        const int k0 = nb0 + ch * 64;
        #pragma unroll
        for (int tl = 0; tl < 4; ++tl) {
            const int code = k0 + tl * 16 + col;
            float me2 = -e2h[code];

            floatx4 acc[4];
            #pragma unroll
            for (int t = 0; t < 4; ++t) acc[t] = (floatx4){me2, me2, me2, me2};

            #pragma unroll
            for (int s = 0; s < 2; ++s) {
                const int segh = 0 * 8 + s * 4 + quad;
                const int segm = 1 * 8 + s * 4 + quad;
                half8 bfh = as_h8(*(const short8*)(cbS + ((size_t)segh * 8192 + code) * 8));
                half8 bfm = as_h8(*(const short8*)(cbS + ((size_t)segm * 8192 + code) * 8));
                #pragma unroll
                for (int t = 0; t < 4; ++t)
                    acc[t] = __builtin_amdgcn_mfma_f32_16x16x32_f16(af[t][0][s], bfh, acc[t], 0, 0, 0); // hh
                #pragma unroll
                for (int t = 0; t < 4; ++t)
                    acc[t] = __builtin_amdgcn_mfma_f32_16x16x32_f16(af[t][0][s], bfm, acc[t], 0, 0, 0); // hm
                #pragma unroll
                for (int t = 0; t < 4; ++t)
                    acc[t] = __builtin_amdgcn_mfma_f32_16x16x32_f16(af[t][1][s], bfh, acc[t], 0, 0, 0); // mh
            }

            #pragma unroll
            for (int t = 0; t < 4; ++t)
                #pragma unroll
                for (int r = 0; r < 4; ++r) {
                    float sc = acc[t][r];
                    bool gt = sc > bestv[t][r];    // strict: earlier code wins
                    bestv[t][r] = gt ? sc   : bestv[t][r];
                    besti[t][r] = gt ? code : besti[t][r];
                }
        }
    }

    // final reduce over the 16 col-candidates per point, in-register:
    // per (t,r), u64-min across the 16 col lanes of each quad group
    // (xor masks 1,2,4,8 stay within the group). Lane with col==t*4+r
    // owns pair (t,r) and writes point m0 + t*16 + quad*4 + r.
    unsigned long long own = 0;
    #pragma unroll
    for (int t = 0; t < 4; ++t)
        #pragma unroll
        for (int r = 0; r < 4; ++r) {
            unsigned u = __float_as_uint(-bestv[t][r]);   // key ascending
            u = ((int)u < 0) ? ~u : (u | 0x80000000u);
            unsigned long long p = ((unsigned long long)u << 32) | (unsigned)besti[t][r];
            #pragma unroll
            for (int msk = 1; msk < 16; msk <<= 1) {
                unsigned long long q = __shfl_xor(p, msk, 64);
                p = (q < p) ? q : p;
            }
            own = (col == t * 4 + r) ? p : own;
        }
    const int mpt = m0 + (col >> 2) * 16 + quad * 4 + (col & 3);
    packedS[(size_t)split * N_PTS + mpt] = own;
}

// ============================================================
// Kernel C: gather + final. 256 blocks x 256; block owns 32
// points, 8 threads/point. Phase 1: thread (p=tid&31, sg=tid>>5)
// reduces split slots {sg*4..sg*4+3} -> sred[8][32]. Phase 2:
// every thread combines the 8 partials. Phase 3: thread handles
// channels sg*8..sg*8+7, fully coalesced; per-wave loss partials.
// Phase 4 (last-block ticket): 256th block re-reduces the 1024
// partials exactly as the old final kernel (bitwise-identical).
// ============================================================
__global__ __launch_bounds__(256)
void vq_gather_kernel(const float* __restrict__ x,
                      const float* __restrict__ cb,
                      const unsigned long long* __restrict__ packedS,
                      float* __restrict__ out,
                      float* __restrict__ part,
                      int* __restrict__ ticket)
{
    __shared__ unsigned long long sred[8][32];
    __shared__ float wloss[4];
    __shared__ int lastFlag;
    const int tid = threadIdx.x;
    const int p   = tid & 31;
    const int sg  = tid >> 5;           // 0..7
    const int n0  = blockIdx.x * 32;
    const int n   = n0 + p;

    {
        unsigned long long v = packedS[(size_t)(sg * 4) * N_PTS + n];
        #pragma unroll
        for (int j = 1; j < 4; ++j) {
            unsigned long long q = packedS[(size_t)(sg * 4 + j) * N_PTS + n];
            v = (q < v) ? q : v;
        }
        sred[sg][p] = v;
    }
    __syncthreads();

    unsigned long long v = sred[0][p];
    #pragma unroll
    for (int s = 1; s < 8; ++s) {
        unsigned long long q = sred[s][p];
        v = (q < v) ? q : v;
    }
    const int idx = (int)(v & 0xFFFFFFFFull);
    if (tid < 32) out[QOUT_N + 2 + n0 + tid] = (float)idx;

    const int c0  = sg * 8;
    const int b   = n >> 10;
    const int hw  = n & 1023;
    const float* xb = x   + (size_t)b * (C_DIM * HWSZ) + hw;
    float*       ob = out + (size_t)b * (C_DIM * HWSZ) + hw;

    float s = 0.0f;
    #pragma unroll
    for (int c4 = 0; c4 < 2; ++c4) {
        float4 q = *(const float4*)(cb + (size_t)idx * C_DIM + c0 + c4 * 4);
        float qa[4] = {q.x, q.y, q.z, q.w};
        #pragma unroll
        for (int j = 0; j < 4; ++j) {
            int c = c0 + c4 * 4 + j;
            float xv = xb[c * HWSZ];
            float d  = qa[j] - xv;          // quant - x (reference rounding)
            s = fmaf(d, d, s);
            ob[c * HWSZ] = xv + d;          // straight-through: x + (q - x)
        }
    }

    #pragma unroll
    for (int off = 32; off > 0; off >>= 1) s += __shfl_down(s, off, 64);
    if ((tid & 63) == 0) part[blockIdx.x * 4 + (tid >> 6)] = s;

    // ---- last-block final reduce (replaces kernel D) ----
    __syncthreads();                     // partials ordered before ticket
    if (tid == 0) {
        __threadfence();                 // release partials, device scope
        int prev = atomicAdd(ticket, 1);
        lastFlag = (prev == 255);
    }
    __syncthreads();
    if (lastFlag) {
        __threadfence();                 // acquire all blocks' partials
        float s2 = part[tid] + part[tid + 256]
                 + part[tid + 512] + part[tid + 768];
        #pragma unroll
        for (int off = 32; off > 0; off >>= 1) s2 += __shfl_down(s2, off, 64);
        if ((tid & 63) == 0) wloss[tid >> 6] = s2;
        __syncthreads();
        if (tid == 0) {
            float m = (wloss[0] + wloss[1] + wloss[2] + wloss[3])
                    * (1.0f / (float)QOUT_N);
            out[QOUT_N]     = m;   // commitment_loss
            out[QOUT_N + 1] = m;   // codebook_loss
        }
    }
}

extern "C" void kernel_launch(void* const* d_in, const int* in_sizes, int n_in,
                              void* d_out, int out_size, void* d_ws, size_t ws_size,
                              hipStream_t stream)
{
    const float* x  = (const float*)d_in[0];   // [8,64,32,32]
    const float* cb = (const float*)d_in[1];   // [8192,64]
    float* out = (float*)d_out;
    char*  ws  = (char*)d_ws;
    (void)ws_size;

    unsigned long long* packedS = (unsigned long long*)(ws + WS_PACK);
    unsigned short* cbS = (unsigned short*)(ws + WS_CBS);
    float* e2h = (float*)(ws + WS_E2H);
    float* part = (float*)(ws + WS_PART);
    int* ticket = (int*)(ws + WS_TICK);

    vq_prep_kernel<<<256, 256, 0, stream>>>(cb, cbS, e2h, ticket);
    vq_argmin_kernel<<<dim3(32, SPLITS), 256, 0, stream>>>(x, cbS, e2h, packedS);
    vq_gather_kernel<<<256, 256, 0, stream>>>(x, cb, packedS, out, part, ticket);
}

// Round 8
// 97.609 us; speedup vs baseline: 1.1663x; 1.1663x over previous
//
#include <hip/hip_runtime.h>

// VQVAE quantize.  x: [8,64,32,32] fp32, codebook: [8192,64] fp32.
// d_out (fp32, concat): [0,524288) quant_out | [524288] commit_loss |
//                       [524289] codebook_loss | [524290,532482) indices
//
// argmin via fp16x2 emulated-fp32 MFMA GEMM (3 terms):
//   v = h + m (2 fp16, exact to ~|v|*2^-23); dot ~= hh + hm + mh
//   score = dot - 0.5*e2[k]  (argmax score == argmin d2; absmax 0 R12-R25)
//
// R25 post-mortem: M=4 regressed argmin to 46.2 (B-traffic halved ->
// load-volume theory dead). Across ALL structures the predictor of
// argmin dur is TOTAL WAVE COUNT: 4096 waves -> 44-46us (R19/R22/R25),
// 8192 waves -> ~36 (R23, inferred). Latency-stall-bound, TLP-starved
// (Occ ~20%, MfmaUtil 20, VALUBusy 29; per-wave issue work only ~2.5K
// cyc vs ~25K cyc measured). R24/R25 also carried ~+13us unexplained
// vs component sums; only unvalidated piece = ticket-merged gather.
// R26: (1) argmin = R23's M=2 no-LDS structure with SPLITS 32->64 ->
// grid (64,64) = 4096 blk x 4 waves = 16384 waves (2x R23). Total
// B-read volume unchanged; af-build doubles (~2us chip-wide).
// (2) prep stays 256-blk (R24). (3) ticket merge REVERTED: R0-style
// separate gather (64 slots, 8/thread) + final kernel.
// R22 lesson: combined VGPR+AGPR budget caps waves/SIMD (unified file).
// R21 lesson: chunk loop stays rolled. R13: 4-tile tl clusters only.

#define N_PTS   8192
#define K_CODES 8192
#define C_DIM   64
#define HWSZ    1024
#define QOUT_N  524288
#define SPLITS  64            // codes per split = 128 = 2 chunks of 64
#define NCH     2             // chunks per split

// ---- workspace layout (bytes) ----
#define WS_PACK  0            // u64 [64][8192]       = 4194304
#define WS_CBS   4194304      // u16 [2*8][8192][8]   = 2097152
#define WS_E2H   6291456      // float [8192]         = 32768
#define WS_PART  6324224      // float [1024]         = 4096

typedef __attribute__((ext_vector_type(8))) short    short8;
typedef __attribute__((ext_vector_type(8))) _Float16 half8;
typedef __attribute__((ext_vector_type(4))) float    floatx4;

__device__ __forceinline__ half8 as_h8(short8 v) {
    return __builtin_bit_cast(half8, v);
}
__device__ __forceinline__ void split2(float v, unsigned short& h,
                                       unsigned short& m) {
    _Float16 hh = (_Float16)v;                     // RNE
    float r = v - (float)hh;
    _Float16 mm = (_Float16)r;
    h = __builtin_bit_cast(unsigned short, hh);
    m = __builtin_bit_cast(unsigned short, mm);
}

// ============================================================
// Kernel A: prep — codebook split + e2. 256 blocks x 256 thr,
// one thread per (code row k, channel octet g): loads 32B
// contiguous (coalesced), split2 x8, two 16B plane writes;
// e2[k] via shfl_xor over the 8 g-lanes of the row.
// Plane layout [p*8+g][k][8], p in {0=h,1=m}: 16B per
// (code, c-octet g) == one MFMA fragment k-group.
// ============================================================
__global__ __launch_bounds__(256)
void vq_prep_kernel(const float* __restrict__ cb,
                    unsigned short* __restrict__ cbS,
                    float* __restrict__ e2h)
{
    const int gt = blockIdx.x * 256 + threadIdx.x;   // 0..65535
    const int k  = gt >> 3;
    const int g  = gt & 7;

    const float* rp = cb + (size_t)k * C_DIM + g * 8;
    float4 a = *(const float4*)(rp);
    float4 b = *(const float4*)(rp + 4);
    float vv[8] = {a.x, a.y, a.z, a.w, b.x, b.y, b.z, b.w};
    unsigned short h8[8], m8[8];
    float s = 0.0f;
    #pragma unroll
    for (int j = 0; j < 8; ++j) {
        s = fmaf(vv[j], vv[j], s);
        split2(vv[j], h8[j], m8[j]);
    }
    *(uint4*)(cbS + ((size_t)(0 * 8 + g) * 8192 + k) * 8) = *(const uint4*)h8;
    *(uint4*)(cbS + ((size_t)(1 * 8 + g) * 8192 + k) * 8) = *(const uint4*)m8;

    #pragma unroll
    for (int msk = 1; msk < 8; msk <<= 1) s += __shfl_xor(s, msk, 64);
    if (g == 0) e2h[k] = 0.5f * s;
}

// ============================================================
// Kernel B: argmin via 16x16x32 f16 MFMA. grid (64 m-blocks,
// 64 splits) = 4096 blocks x 256 threads (4 waves) = 16384
// waves (TLP is the measured lever). Wave owns 32 points
// (2 tiles of 16) x 128 codes. NO LDS, NO barriers: per
// 16-code tile, bf[2][2] (4x dwordx4) and e2 are read straight
// from global (L1/L2-resident; co-resident blocks share the
// split). A-frags from x in regs (~32 regs). lb(256,4).
// Final reduce via __shfl_xor u64 min (8 owner cols).
// Layouts (verified m89/m91/m120): A[m=lane&15][k=quad*8+j],
// B[k=quad*8+j][n=lane&15], C: col=lane&15, row=quad*4+reg.
// ============================================================
__global__ __launch_bounds__(256, 4)
void vq_argmin_kernel(const float* __restrict__ x,
                      const unsigned short* __restrict__ cbS,
                      const float* __restrict__ e2h,
                      unsigned long long* __restrict__ packedS)
{
    const int tid   = threadIdx.x;       // 0..255
    const int lane  = tid & 63;
    const int w     = tid >> 6;          // 0..3
    const int col   = lane & 15;
    const int quad  = lane >> 4;
    const int mb    = blockIdx.x;        // 0..63
    const int split = blockIdx.y;        // 0..63
    const int m0    = mb * 128 + w * 32;
    const int nb0   = split * 128;

    // A fragments straight from x: pt = m0 + t*16 + col, channel
    // c = s*32 + quad*8 + j (matches MFMA k = quad*8+j per s-step).
    // 128 pts per block never cross an image (1024 pts/image).
    const int bimg = m0 >> 10;
    const int hw0  = m0 & 1023;
    const float* xb = x + (size_t)bimg * (C_DIM * HWSZ);
    half8 af[2][2][2];                   // [tile][plane][s] = 32 regs
    #pragma unroll
    for (int t = 0; t < 2; ++t) {
        const int hw = hw0 + t * 16 + col;
        #pragma unroll
        for (int s = 0; s < 2; ++s) {
            unsigned short h8[8], m8[8];
            #pragma unroll
            for (int j = 0; j < 8; ++j) {
                float v = xb[(size_t)(s * 32 + quad * 8 + j) * HWSZ + hw];
                split2(v, h8[j], m8[j]);
            }
            af[t][0][s] = as_h8(*(const short8*)h8);
            af[t][1][s] = as_h8(*(const short8*)m8);
        }
    }

    float bestv[2][4];
    int   besti[2][4];
    #pragma unroll
    for (int t = 0; t < 2; ++t)
        #pragma unroll
        for (int r = 0; r < 4; ++r) {
            bestv[t][r] = __uint_as_float(0xFF800000u);  // -inf
            besti[t][r] = 0;
        }

    // main loop: 2 chunks x 4 tiles of 16 codes; everything from
    // global (L1/L2). Rolled ch loop (R21: unroll -> spill); tl
    // loop unrolled so the compiler pipelines loads across tiles.
    #pragma clang loop unroll(disable)
    for (int ch = 0; ch < NCH; ++ch) {
        const int k0 = nb0 + ch * 64;
        #pragma unroll
        for (int tl = 0; tl < 4; ++tl) {
            const int code = k0 + tl * 16 + col;
            half8 bf[2][2];
            #pragma unroll
            for (int p = 0; p < 2; ++p)
                #pragma unroll
                for (int s = 0; s < 2; ++s) {
                    int seg = p * 8 + s * 4 + quad;
                    bf[p][s] = as_h8(*(const short8*)(cbS + ((size_t)seg * 8192 + code) * 8));
                }
            float me2 = -e2h[code];

            floatx4 acc[2];
            #pragma unroll
            for (int t = 0; t < 2; ++t) acc[t] = (floatx4){me2, me2, me2, me2};

            #pragma unroll
            for (int s = 0; s < 2; ++s) {
                #pragma unroll
                for (int t = 0; t < 2; ++t)
                    acc[t] = __builtin_amdgcn_mfma_f32_16x16x32_f16(af[t][0][s], bf[0][s], acc[t], 0, 0, 0); // hh
                #pragma unroll
                for (int t = 0; t < 2; ++t)
                    acc[t] = __builtin_amdgcn_mfma_f32_16x16x32_f16(af[t][0][s], bf[1][s], acc[t], 0, 0, 0); // hm
                #pragma unroll
                for (int t = 0; t < 2; ++t)
                    acc[t] = __builtin_amdgcn_mfma_f32_16x16x32_f16(af[t][1][s], bf[0][s], acc[t], 0, 0, 0); // mh
            }

            #pragma unroll
            for (int t = 0; t < 2; ++t)
                #pragma unroll
                for (int r = 0; r < 4; ++r) {
                    float sc = acc[t][r];
                    bool gt = sc > bestv[t][r];    // strict: earlier code wins
                    bestv[t][r] = gt ? sc   : bestv[t][r];
                    besti[t][r] = gt ? code : besti[t][r];
                }
        }
    }

    // final reduce over the 16 col-candidates per point, in-register:
    // per (t,r), u64-min across the 16 col lanes of each quad group
    // (xor masks 1,2,4,8 stay within the group). Lane with col==t*4+r
    // (col 0..7) owns pair (t,r) and writes point m0+t*16+quad*4+r.
    unsigned long long own = 0;
    #pragma unroll
    for (int t = 0; t < 2; ++t)
        #pragma unroll
        for (int r = 0; r < 4; ++r) {
            unsigned u = __float_as_uint(-bestv[t][r]);   // key ascending
            u = ((int)u < 0) ? ~u : (u | 0x80000000u);
            unsigned long long p = ((unsigned long long)u << 32) | (unsigned)besti[t][r];
            #pragma unroll
            for (int msk = 1; msk < 16; msk <<= 1) {
                unsigned long long q = __shfl_xor(p, msk, 64);
                p = (q < p) ? q : p;
            }
            own = (col == t * 4 + r) ? p : own;
        }
    if (col < 8) {
        const int mpt = m0 + (col >> 2) * 16 + quad * 4 + (col & 3);
        packedS[(size_t)split * N_PTS + mpt] = own;
    }
}

// ============================================================
// Kernel C: gather. 256 blocks x 256; block owns 32 points,
// 8 threads/point. Phase 1: thread (p=tid&31, sg=tid>>5) reduces
// split slots {sg*8 .. sg*8+7} -> sred[8][32]. Phase 2: every
// thread combines the 8 partials. Phase 3: thread handles
// channels sg*8..sg*8+7, fully coalesced; per-wave loss partials.
// ============================================================
__global__ __launch_bounds__(256)
void vq_gather_kernel(const float* __restrict__ x,
                      const float* __restrict__ cb,
                      const unsigned long long* __restrict__ packedS,
                      float* __restrict__ out,
                      float* __restrict__ part)
{
    __shared__ unsigned long long sred[8][32];
    const int tid = threadIdx.x;
    const int p   = tid & 31;
    const int sg  = tid >> 5;           // 0..7
    const int n0  = blockIdx.x * 32;
    const int n   = n0 + p;

    {
        unsigned long long v = packedS[(size_t)(sg * 8) * N_PTS + n];
        #pragma unroll
        for (int j = 1; j < 8; ++j) {
            unsigned long long q = packedS[(size_t)(sg * 8 + j) * N_PTS + n];
            v = (q < v) ? q : v;
        }
        sred[sg][p] = v;
    }
    __syncthreads();

    unsigned long long v = sred[0][p];
    #pragma unroll
    for (int s = 1; s < 8; ++s) {
        unsigned long long q = sred[s][p];
        v = (q < v) ? q : v;
    }
    const int idx = (int)(v & 0xFFFFFFFFull);
    if (tid < 32) out[QOUT_N + 2 + n0 + tid] = (float)idx;

    const int c0  = sg * 8;
    const int b   = n >> 10;
    const int hw  = n & 1023;
    const float* xb = x   + (size_t)b * (C_DIM * HWSZ) + hw;
    float*       ob = out + (size_t)b * (C_DIM * HWSZ) + hw;

    float s = 0.0f;
    #pragma unroll
    for (int c4 = 0; c4 < 2; ++c4) {
        float4 q = *(const float4*)(cb + (size_t)idx * C_DIM + c0 + c4 * 4);
        float qa[4] = {q.x, q.y, q.z, q.w};
        #pragma unroll
        for (int j = 0; j < 4; ++j) {
            int c = c0 + c4 * 4 + j;
            float xv = xb[c * HWSZ];
            float d  = qa[j] - xv;          // quant - x (reference rounding)
            s = fmaf(d, d, s);
            ob[c * HWSZ] = xv + d;          // straight-through: x + (q - x)
        }
    }

    #pragma unroll
    for (int off = 32; off > 0; off >>= 1) s += __shfl_down(s, off, 64);
    if ((tid & 63) == 0) part[blockIdx.x * 4 + (tid >> 6)] = s;
}

// ============================================================
// Kernel D: final loss reduction (1024 partials -> 2 scalars).
// ============================================================
__global__ __launch_bounds__(256)
void vq_final_kernel(const float* __restrict__ part, float* __restrict__ out)
{
    __shared__ float w[4];
    float s = part[threadIdx.x] + part[threadIdx.x + 256]
            + part[threadIdx.x + 512] + part[threadIdx.x + 768];
    #pragma unroll
    for (int off = 32; off > 0; off >>= 1) s += __shfl_down(s, off, 64);
    if ((threadIdx.x & 63) == 0) w[threadIdx.x >> 6] = s;
    __syncthreads();
    if (threadIdx.x == 0) {
        float m = (w[0] + w[1] + w[2] + w[3]) * (1.0f / (float)QOUT_N);
        out[QOUT_N]     = m;   // commitment_loss
        out[QOUT_N + 1] = m;   // codebook_loss
    }
}

extern "C" void kernel_launch(void* const* d_in, const int* in_sizes, int n_in,
                              void* d_out, int out_size, void* d_ws, size_t ws_size,
                              hipStream_t stream)
{
    const float* x  = (const float*)d_in[0];   // [8,64,32,32]
    const float* cb = (const float*)d_in[1];   // [8192,64]
    float* out = (float*)d_out;
    char*  ws  = (char*)d_ws;
    (void)ws_size;

    unsigned long long* packedS = (unsigned long long*)(ws + WS_PACK);
    unsigned short* cbS = (unsigned short*)(ws + WS_CBS);
    float* e2h = (float*)(ws + WS_E2H);
    float* part = (float*)(ws + WS_PART);

    vq_prep_kernel<<<256, 256, 0, stream>>>(cb, cbS, e2h);
    vq_argmin_kernel<<<dim3(64, SPLITS), 256, 0, stream>>>(x, cbS, e2h, packedS);
    vq_gather_kernel<<<256, 256, 0, stream>>>(x, cb, packedS, out, part);
    vq_final_kernel<<<1, 256, 0, stream>>>(part, out);
}

// Round 9
// 94.161 us; speedup vs baseline: 1.2090x; 1.0366x over previous
//
#include <hip/hip_runtime.h>

// VQVAE quantize.  x: [8,64,32,32] fp32, codebook: [8192,64] fp32.
// d_out (fp32, concat): [0,524288) quant_out | [524288] commit_loss |
//                       [524289] codebook_loss | [524290,532482) indices
//
// argmin via fp16x2 emulated-fp32 MFMA GEMM (3 terms):
//   v = h + m (2 fp16, exact to ~|v|*2^-23); dot ~= hh + hm + mh
//   score = dot - 0.5*e2[k]  (argmax score == argmin d2; absmax 0 R12-R26)
//
// R26 post-mortem: 16384 waves == 8192 waves -> TLP saturated. Ledger:
// argmin ~36-46us across ALL structures; every pipe <30%, HBM 3%, L2
// ~6 TB/s; issue/latency/BW models all give 4-8us -> ~5x unexplained
// stall. Untested mechanisms: (a) per-tile load->vmcnt->MFMA serial
// codegen (each tile pays ~250cyc L2 latency serially, 16 tiles/wave);
// (b) split working set scattered over all 8 XCD L2s by dispatch
// round-robin. R27: (1) flat rolled tile-pair loop w/ static A/B reg
// buffers - prefetch tile n+1 bf+e2 during tile n MFMA (no LDS, no
// barriers, ~110 VGPR lb(256,4)); (2) XCD swizzle: split = (bx&7) |
// ((by&3)<<3) -> all 64 mb-blocks of a split on ONE XCD (cbS 64KB in
// one L2). Geometry = R23 best-measured: SPLITS=32, 2048 blk, M=2.
// R22 lesson: combined VGPR+AGPR budget caps waves/SIMD (unified file).
// R21 lesson: loops rolled, static reg names. R13: small MFMA clusters.

#define N_PTS   8192
#define K_CODES 8192
#define C_DIM   64
#define HWSZ    1024
#define QOUT_N  524288
#define SPLITS  32            // codes per split = 256 = 16 tiles of 16
#define NTILES  16

// ---- workspace layout (bytes) ----
#define WS_PACK  0            // u64 [32][8192]       = 2097152
#define WS_CBS   2097152      // u16 [2*8][8192][8]   = 2097152
#define WS_E2H   4194304      // float [8192]         = 32768
#define WS_PART  4227072      // float [1024]         = 4096

typedef __attribute__((ext_vector_type(8))) short    short8;
typedef __attribute__((ext_vector_type(8))) _Float16 half8;
typedef __attribute__((ext_vector_type(4))) float    floatx4;

__device__ __forceinline__ half8 as_h8(short8 v) {
    return __builtin_bit_cast(half8, v);
}
__device__ __forceinline__ void split2(float v, unsigned short& h,
                                       unsigned short& m) {
    _Float16 hh = (_Float16)v;                     // RNE
    float r = v - (float)hh;
    _Float16 mm = (_Float16)r;
    h = __builtin_bit_cast(unsigned short, hh);
    m = __builtin_bit_cast(unsigned short, mm);
}

// ============================================================
// Kernel A: prep — codebook split + e2. 256 blocks x 256 thr,
// one thread per (code row k, channel octet g): loads 32B
// contiguous (coalesced), split2 x8, two 16B plane writes;
// e2[k] via shfl_xor over the 8 g-lanes of the row.
// Plane layout [p*8+g][k][8], p in {0=h,1=m}: 16B per
// (code, c-octet g) == one MFMA fragment k-group.
// ============================================================
__global__ __launch_bounds__(256)
void vq_prep_kernel(const float* __restrict__ cb,
                    unsigned short* __restrict__ cbS,
                    float* __restrict__ e2h)
{
    const int gt = blockIdx.x * 256 + threadIdx.x;   // 0..65535
    const int k  = gt >> 3;
    const int g  = gt & 7;

    const float* rp = cb + (size_t)k * C_DIM + g * 8;
    float4 a = *(const float4*)(rp);
    float4 b = *(const float4*)(rp + 4);
    float vv[8] = {a.x, a.y, a.z, a.w, b.x, b.y, b.z, b.w};
    unsigned short h8[8], m8[8];
    float s = 0.0f;
    #pragma unroll
    for (int j = 0; j < 8; ++j) {
        s = fmaf(vv[j], vv[j], s);
        split2(vv[j], h8[j], m8[j]);
    }
    *(uint4*)(cbS + ((size_t)(0 * 8 + g) * 8192 + k) * 8) = *(const uint4*)h8;
    *(uint4*)(cbS + ((size_t)(1 * 8 + g) * 8192 + k) * 8) = *(const uint4*)m8;

    #pragma unroll
    for (int msk = 1; msk < 8; msk <<= 1) s += __shfl_xor(s, msk, 64);
    if (g == 0) e2h[k] = 0.5f * s;
}

// ============================================================
// Kernel B: argmin via 16x16x32 f16 MFMA. grid (64,32) = 2048
// blocks x 256 threads (4 waves). XCD swizzle: split=(bx&7)|
// ((by&3)<<3), mb=(bx>>3)|((by>>2)<<3) -> all 64 blocks of a
// split share dispatch%8 == one XCD L2. Wave owns 32 points
// (2 tiles) x 256 codes = 16 code-tiles of 16, processed by a
// ROLLED pair-loop with static A/B register buffers: prefetch
// tile n+1 (4 bf + e2) while MFMAing tile n — breaks the
// per-tile load->vmcnt->MFMA serial chain. NO LDS, no barriers.
// Final reduce via __shfl_xor u64 min (8 owner cols).
// Layouts (verified m89/m91/m120): A[m=lane&15][k=quad*8+j],
// B[k=quad*8+j][n=lane&15], C: col=lane&15, row=quad*4+reg.
// ============================================================
__global__ __launch_bounds__(256, 4)
void vq_argmin_kernel(const float* __restrict__ x,
                      const unsigned short* __restrict__ cbS,
                      const float* __restrict__ e2h,
                      unsigned long long* __restrict__ packedS)
{
    const int tid   = threadIdx.x;       // 0..255
    const int lane  = tid & 63;
    const int w     = tid >> 6;          // 0..3
    const int col   = lane & 15;
    const int quad  = lane >> 4;
    const int bx    = blockIdx.x;        // 0..63
    const int by    = blockIdx.y;        // 0..31
    const int split = (bx & 7) | ((by & 3) << 3);    // 0..31, fixed per XCD
    const int mb    = (bx >> 3) | ((by >> 2) << 3);  // 0..63
    const int m0    = mb * 128 + w * 32;
    const int nb0   = split * 256;

    // A fragments straight from x: pt = m0 + t*16 + col, channel
    // c = s*32 + quad*8 + j (matches MFMA k = quad*8+j per s-step).
    // 128 pts per block never cross an image (1024 pts/image).
    const int bimg = m0 >> 10;
    const int hw0  = m0 & 1023;
    const float* xb = x + (size_t)bimg * (C_DIM * HWSZ);
    half8 af[2][2][2];                   // [tile][plane][s] = 32 regs
    #pragma unroll
    for (int t = 0; t < 2; ++t) {
        const int hw = hw0 + t * 16 + col;
        #pragma unroll
        for (int s = 0; s < 2; ++s) {
            unsigned short h8[8], m8[8];
            #pragma unroll
            for (int j = 0; j < 8; ++j) {
                float v = xb[(size_t)(s * 32 + quad * 8 + j) * HWSZ + hw];
                split2(v, h8[j], m8[j]);
            }
            af[t][0][s] = as_h8(*(const short8*)h8);
            af[t][1][s] = as_h8(*(const short8*)m8);
        }
    }

    float bestv[2][4];
    int   besti[2][4];
    #pragma unroll
    for (int t = 0; t < 2; ++t)
        #pragma unroll
        for (int r = 0; r < 4; ++r) {
            bestv[t][r] = __uint_as_float(0xFF800000u);  // -inf
            besti[t][r] = 0;
        }

    // tile load: 4x dwordx4 (bf) + 1 scalar (e2) into named regs.
    auto loadT = [&](int tile, half8 (&bf)[2][2], float& me) {
        const int code = nb0 + tile * 16 + col;
        #pragma unroll
        for (int p = 0; p < 2; ++p)
            #pragma unroll
            for (int s = 0; s < 2; ++s) {
                int seg = p * 8 + s * 4 + quad;
                bf[p][s] = as_h8(*(const short8*)(cbS + ((size_t)seg * 8192 + code) * 8));
            }
        me = -e2h[code];
    };
    // tile compute: 12 MFMA + 8 selects.
    auto compT = [&](int tile, const half8 (&bf)[2][2], float me) {
        const int code = nb0 + tile * 16 + col;
        floatx4 acc[2];
        #pragma unroll
        for (int t = 0; t < 2; ++t) acc[t] = (floatx4){me, me, me, me};
        #pragma unroll
        for (int s = 0; s < 2; ++s) {
            #pragma unroll
            for (int t = 0; t < 2; ++t)
                acc[t] = __builtin_amdgcn_mfma_f32_16x16x32_f16(af[t][0][s], bf[0][s], acc[t], 0, 0, 0); // hh
            #pragma unroll
            for (int t = 0; t < 2; ++t)
                acc[t] = __builtin_amdgcn_mfma_f32_16x16x32_f16(af[t][0][s], bf[1][s], acc[t], 0, 0, 0); // hm
            #pragma unroll
            for (int t = 0; t < 2; ++t)
                acc[t] = __builtin_amdgcn_mfma_f32_16x16x32_f16(af[t][1][s], bf[0][s], acc[t], 0, 0, 0); // mh
        }
        #pragma unroll
        for (int t = 0; t < 2; ++t)
            #pragma unroll
            for (int r = 0; r < 4; ++r) {
                float sc = acc[t][r];
                bool gt = sc > bestv[t][r];        // strict: earlier code wins
                bestv[t][r] = gt ? sc   : bestv[t][r];
                besti[t][r] = gt ? code : besti[t][r];
            }
    };

    // rolled pair-loop, 1-deep register prefetch (static A/B names).
    half8 bfA[2][2], bfB[2][2];
    float meA, meB;
    loadT(0, bfA, meA);
    #pragma clang loop unroll(disable)
    for (int i = 0; i < NTILES / 2; ++i) {
        loadT(2 * i + 1, bfB, meB);          // prefetch odd tile
        compT(2 * i, bfA, meA);              // compute even tile
        if (i < NTILES / 2 - 1)
            loadT(2 * i + 2, bfA, meA);      // prefetch next even tile
        compT(2 * i + 1, bfB, meB);          // compute odd tile
    }

    // final reduce over the 16 col-candidates per point, in-register:
    // per (t,r), u64-min across the 16 col lanes of each quad group
    // (xor masks 1,2,4,8 stay within the group). Lane with col==t*4+r
    // (col 0..7) owns pair (t,r) and writes point m0+t*16+quad*4+r.
    unsigned long long own = 0;
    #pragma unroll
    for (int t = 0; t < 2; ++t)
        #pragma unroll
        for (int r = 0; r < 4; ++r) {
            unsigned u = __float_as_uint(-bestv[t][r]);   // key ascending
            u = ((int)u < 0) ? ~u : (u | 0x80000000u);
            unsigned long long p = ((unsigned long long)u << 32) | (unsigned)besti[t][r];
            #pragma unroll
            for (int msk = 1; msk < 16; msk <<= 1) {
                unsigned long long q = __shfl_xor(p, msk, 64);
                p = (q < p) ? q : p;
            }
            own = (col == t * 4 + r) ? p : own;
        }
    if (col < 8) {
        const int mpt = m0 + (col >> 2) * 16 + quad * 4 + (col & 3);
        packedS[(size_t)split * N_PTS + mpt] = own;
    }
}

// ============================================================
// Kernel C: gather. 256 blocks x 256; block owns 32 points,
// 8 threads/point. Phase 1: thread (p=tid&31, sg=tid>>5) reduces
// split slots {sg*4 .. sg*4+3} -> sred[8][32]. Phase 2: every
// thread combines the 8 partials. Phase 3: thread handles
// channels sg*8..sg*8+7, fully coalesced; per-wave loss partials.
// ============================================================
__global__ __launch_bounds__(256)
void vq_gather_kernel(const float* __restrict__ x,
                      const float* __restrict__ cb,
                      const unsigned long long* __restrict__ packedS,
                      float* __restrict__ out,
                      float* __restrict__ part)
{
    __shared__ unsigned long long sred[8][32];
    const int tid = threadIdx.x;
    const int p   = tid & 31;
    const int sg  = tid >> 5;           // 0..7
    const int n0  = blockIdx.x * 32;
    const int n   = n0 + p;

    {
        unsigned long long v = packedS[(size_t)(sg * 4) * N_PTS + n];
        #pragma unroll
        for (int j = 1; j < 4; ++j) {
            unsigned long long q = packedS[(size_t)(sg * 4 + j) * N_PTS + n];
            v = (q < v) ? q : v;
        }
        sred[sg][p] = v;
    }
    __syncthreads();

    unsigned long long v = sred[0][p];
    #pragma unroll
    for (int s = 1; s < 8; ++s) {
        unsigned long long q = sred[s][p];
        v = (q < v) ? q : v;
    }
    const int idx = (int)(v & 0xFFFFFFFFull);
    if (tid < 32) out[QOUT_N + 2 + n0 + tid] = (float)idx;

    const int c0  = sg * 8;
    const int b   = n >> 10;
    const int hw  = n & 1023;
    const float* xb = x   + (size_t)b * (C_DIM * HWSZ) + hw;
    float*       ob = out + (size_t)b * (C_DIM * HWSZ) + hw;

    float s = 0.0f;
    #pragma unroll
    for (int c4 = 0; c4 < 2; ++c4) {
        float4 q = *(const float4*)(cb + (size_t)idx * C_DIM + c0 + c4 * 4);
        float qa[4] = {q.x, q.y, q.z, q.w};
        #pragma unroll
        for (int j = 0; j < 4; ++j) {
            int c = c0 + c4 * 4 + j;
            float xv = xb[c * HWSZ];
            float d  = qa[j] - xv;          // quant - x (reference rounding)
            s = fmaf(d, d, s);
            ob[c * HWSZ] = xv + d;          // straight-through: x + (q - x)
        }
    }

    #pragma unroll
    for (int off = 32; off > 0; off >>= 1) s += __shfl_down(s, off, 64);
    if ((tid & 63) == 0) part[blockIdx.x * 4 + (tid >> 6)] = s;
}

// ============================================================
// Kernel D: final loss reduction (1024 partials -> 2 scalars).
// ============================================================
__global__ __launch_bounds__(256)
void vq_final_kernel(const float* __restrict__ part, float* __restrict__ out)
{
    __shared__ float w[4];
    float s = part[threadIdx.x] + part[threadIdx.x + 256]
            + part[threadIdx.x + 512] + part[threadIdx.x + 768];
    #pragma unroll
    for (int off = 32; off > 0; off >>= 1) s += __shfl_down(s, off, 64);
    if ((threadIdx.x & 63) == 0) w[threadIdx.x >> 6] = s;
    __syncthreads();
    if (threadIdx.x == 0) {
        float m = (w[0] + w[1] + w[2] + w[3]) * (1.0f / (float)QOUT_N);
        out[QOUT_N]     = m;   // commitment_loss
        out[QOUT_N + 1] = m;   // codebook_loss
    }
}

extern "C" void kernel_launch(void* const* d_in, const int* in_sizes, int n_in,
                              void* d_out, int out_size, void* d_ws, size_t ws_size,
                              hipStream_t stream)
{
    const float* x  = (const float*)d_in[0];   // [8,64,32,32]
    const float* cb = (const float*)d_in[1];   // [8192,64]
    float* out = (float*)d_out;
    char*  ws  = (char*)d_ws;
    (void)ws_size;

    unsigned long long* packedS = (unsigned long long*)(ws + WS_PACK);
    unsigned short* cbS = (unsigned short*)(ws + WS_CBS);
    float* e2h = (float*)(ws + WS_E2H);
    float* part = (float*)(ws + WS_PART);

    vq_prep_kernel<<<256, 256, 0, stream>>>(cb, cbS, e2h);
    vq_argmin_kernel<<<dim3(64, SPLITS), 256, 0, stream>>>(x, cbS, e2h, packedS);
    vq_gather_kernel<<<256, 256, 0, stream>>>(x, cb, packedS, out, part);
    vq_final_kernel<<<1, 256, 0, stream>>>(part, out);
}